// Round 18
// baseline (358.468 us; speedup 1.0000x reference)
//
#include <hip/hip_runtime.h>
#include <hip/hip_bf16.h>
#include <stdint.h>

typedef __hip_bfloat16 bf16;
typedef __attribute__((ext_vector_type(8))) short short8;  // 8 bf16 = 4 VGPR
typedef __attribute__((ext_vector_type(4))) float f32x4;

#define DEVFN __device__ __forceinline__

// B=8, N=1024, DIM=768, HEADS=8, HEAD_DIM=96, S=16, CH=3. fp32 in/out.
constexpr float SCALE = 0.10206207261596577f;   // 96^-0.5

DEVFN short8 as_s8(uint4 u) { union { uint4 a; short8 b; } x; x.a = u; return x.b; }

DEVFN f32x4 mfma16(uint4 a, uint4 b, f32x4 c) {
  return __builtin_amdgcn_mfma_f32_16x16x32_bf16(as_s8(a), as_s8(b), c, 0, 0, 0);
}

DEVFN uint4 ldg4(const bf16* p) { return *(const uint4*)p; }

DEVFN void splitw(float x, ushort& h, ushort& l) {
  const float hi = __bfloat162float(__float2bfloat16(x));
  h = (ushort)(__float_as_uint(hi) >> 16);
  l = (ushort)(__float_as_uint(__bfloat162float(__float2bfloat16(x - hi))) >> 16);
}

// ---------------------------------------------------------------------------
// Kernel A: 3x3 SAME conv on (16,16,3) image view; head = y>>1,
// d = (y&1)*48 + x*3 + c.  fp32 in -> bf16 qh/kh/vh [B*H][1024][96].
// ---------------------------------------------------------------------------
__global__ __launch_bounds__(256) void conv_kernel(
    const float* __restrict__ q, const float* __restrict__ k, const float* __restrict__ v,
    const float* __restrict__ cw,
    bf16* __restrict__ qh, bf16* __restrict__ kh, bf16* __restrict__ vh)
{
  __shared__ float img[3][768];
  __shared__ float wsm[81];
  const int t = threadIdx.x;
  const size_t pos = blockIdx.x;
  const int b = blockIdx.x >> 10;
  const int n = blockIdx.x & 1023;

  {
    const float* s0 = q + pos * 768;
    const float* s1 = k + pos * 768;
    const float* s2 = v + pos * 768;
    img[0][t] = s0[t]; img[0][t + 256] = s0[t + 256]; img[0][t + 512] = s0[t + 512];
    img[1][t] = s1[t]; img[1][t + 256] = s1[t + 256]; img[1][t + 512] = s1[t + 512];
    img[2][t] = s2[t]; img[2][t + 256] = s2[t + 256]; img[2][t + 512] = s2[t + 512];
  }
  if (t < 81) wsm[t] = cw[t];
  __syncthreads();

  const int x    = t & 15;
  const int y    = t >> 4;
  const int head = y >> 1;
  const int d0   = (y & 1) * 48 + x * 3;
  const size_t obase = (((size_t)(b * 8 + head)) * 1024 + n) * 96 + d0;

  #pragma unroll
  for (int s3 = 0; s3 < 3; ++s3) {
    float a0 = 0.f, a1 = 0.f, a2 = 0.f;
    #pragma unroll
    for (int dy = 0; dy < 3; ++dy) {
      const int iy = y + dy - 1;
      if ((unsigned)iy < 16u) {
        #pragma unroll
        for (int dx = 0; dx < 3; ++dx) {
          const int ix = x + dx - 1;
          if ((unsigned)ix < 16u) {
            const int ib = iy * 48 + ix * 3;
            const int wb = (dy * 3 + dx) * 9;
            #pragma unroll
            for (int ci = 0; ci < 3; ++ci) {
              const float val = img[s3][ib + ci];
              a0 = fmaf(val, wsm[wb + ci * 3 + 0], a0);
              a1 = fmaf(val, wsm[wb + ci * 3 + 1], a1);
              a2 = fmaf(val, wsm[wb + ci * 3 + 2], a2);
            }
          }
        }
      }
    }
    bf16* dst = (s3 == 0) ? qh : (s3 == 1) ? kh : vh;
    dst[obase]     = __float2bfloat16(a0);
    dst[obase + 1] = __float2bfloat16(a1);
    dst[obase + 2] = __float2bfloat16(a2);
  }
}

// ---------------------------------------------------------------------------
// Kernel T: transpose vh [bg][1024 n][96 d] -> vt [bg][96 d][1024 n] (bf16)
// ---------------------------------------------------------------------------
__global__ __launch_bounds__(256) void vtrans_kernel(
    const bf16* __restrict__ vh, bf16* __restrict__ vt)
{
  __shared__ unsigned T[64][52];
  const int t = threadIdx.x;
  const int bg = blockIdx.x >> 4;
  const int n0 = (blockIdx.x & 15) << 6;
  const bf16* src = vh + ((size_t)bg * 1024 + n0) * 96;
  #pragma unroll
  for (int it = 0; it < 3; ++it) {
    const int i = t + it * 256;
    const int r = i / 12, j = i - r * 12;
    ((uint4*)&T[r][0])[j] = ((const uint4*)(src + (size_t)r * 96))[j];
  }
  __syncthreads();
  #pragma unroll
  for (int it = 0; it < 3; ++it) {
    const int i = t + it * 256;
    const int d = i >> 3, c = i & 7;
    unsigned wo[4];
    #pragma unroll
    for (int p = 0; p < 4; ++p) {
      const unsigned lo = T[c * 8 + p * 2    ][d >> 1];
      const unsigned hi = T[c * 8 + p * 2 + 1][d >> 1];
      const unsigned a  = (d & 1) ? (lo >> 16)          : (lo & 0xffffu);
      const unsigned bs = (d & 1) ? (hi & 0xffff0000u)  : (hi << 16);
      wo[p] = a | bs;
    }
    uint4 out4; out4.x = wo[0]; out4.y = wo[1]; out4.z = wo[2]; out4.w = wo[3];
    *(uint4*)(vt + ((size_t)bg * 96 + d) * 1024 + n0 + c * 8) = out4;
  }
}

// ---------------------------------------------------------------------------
// Kernel F: fused attention — EXACT R2 structure (155.5 µs proven):
// one block per (b, 32-row n-tile); 8 waves; wave w = (nh=w>>2, mq=w&3);
// K frags depth-3 pipelined; single Am + two barriers per m-tile; V batch-
// issued 12-deep before the Am barrier. Epilogue writes X pre-split as
// hi/lo bf16 (Xh/Xl) for proj3 (identical numerics to fp32->split2 path).
//
// MODE 0 = real kernel. MODE 3 (stale-K/V compute-floor probe) retained in
// source for a future ablation round; NOT instantiated this round.
// ---------------------------------------------------------------------------
template<int MODE>
__global__ __launch_bounds__(512, 2) void attn_fused_t(
    const bf16* __restrict__ qh, const bf16* __restrict__ kh, const bf16* __restrict__ vt,
    const float* __restrict__ rw, const float* __restrict__ rb,
    const float* __restrict__ bng, const float* __restrict__ bnb,
    const float* __restrict__ bnm, const float* __restrict__ bnv,
    ushort* __restrict__ Xh, ushort* __restrict__ Xl)
{
  constexpr int REPS = (MODE == 3) ? 2 : 1;

  __shared__ bf16  Qsm[8][32][104];   // 53,248 B (pad 104: 8 distinct bank starts)
  __shared__ bf16  Am[8][32][64];     // 32,768 B (m XOR-swizzled by (n&7)<<3)
  __shared__ float Lsm[8][32];
  __shared__ float Linv[8][32];
  __shared__ float Wm[8][8];
  __shared__ float invg[8], cg[8];

  const int t    = threadIdx.x;
  const int b    = blockIdx.x & 7;    // XCD swizzle: batch b -> XCD b
  const int nt   = blockIdx.x >> 3;   // 0..31
  const int n0   = nt << 5;
  const int w    = t >> 6;            // wave 0..7
  const int lane = t & 63;
  const int l15  = lane & 15;
  const int quad = lane >> 4;
  const int nh   = w >> 2;            // QK n-half (0,1)
  const int mq   = w & 3;             // QK m-quadrant (0..3)

  // ---- stage Q (8 heads x 32 rows x 96) into LDS ----
  {
    const int row  = t >> 1;          // 0..255 = h*32 + n
    const int half = t & 1;
    const int hh = row >> 5, nn = row & 31;
    const bf16* src = qh + (((size_t)(b * 8 + hh)) * 1024 + n0 + nn) * 96 + half * 48;
    bf16* dst = &Qsm[hh][nn][half * 48];
    #pragma unroll
    for (int j = 0; j < 6; ++j)
      ((uint4*)dst)[j] = ((const uint4*)src)[j];
  }
  if (t < 64) Wm[t >> 3][t & 7] = rw[t];
  if (t < 8) {
    const float iv = bng[t] * rsqrtf(bnv[t] + 1e-3f);
    invg[t] = iv;
    cg[t]   = iv * (rb[t] - bnm[t]) + bnb[t];
  }
  if (t < 256) Lsm[t >> 5][t & 31] = 0.f;
  __syncthreads();

  const bf16* kbase = kh + (size_t)(b * 8) * 98304;           // 1024*96 per head
  const size_t kfragoff = (size_t)(mq * 16 + l15) * 96 + quad * 8;
  const int qrow = nh * 16 + l15;

  // ---- K frag pipeline: kf[h] = 3 x uint4 covering k=0..95 for head h ----
  uint4 kf[8][3];
  #pragma unroll
  for (int hp = 0; hp < ((MODE == 3) ? 4 : 3); ++hp) {
    const bf16* kp = kbase + (size_t)hp * 98304 + kfragoff;   // mt=0
    kf[hp][0] = ldg4(kp); kf[hp][1] = ldg4(kp + 32); kf[hp][2] = ldg4(kp + 64);
  }

  uint4 vf[6][2];
  if constexpr (MODE == 3) {       // stale V: loaded once, reused every m-tile
    #pragma unroll
    for (int dt = 0; dt < 6; ++dt) {
      const bf16* vp = vt + (((size_t)(b * 8 + w)) * 96 + dt * 16 + l15) * 1024 + quad * 8;
      vf[dt][0] = ldg4(vp); vf[dt][1] = ldg4(vp + 32);
    }
  }

  f32x4 oacc[2][6];
  #pragma unroll
  for (int i = 0; i < 2; ++i)
    #pragma unroll
    for (int j = 0; j < 6; ++j) oacc[i][j] = (f32x4){0.f, 0.f, 0.f, 0.f};

  const int nrow = nh * 16 + quad * 4;

  #pragma unroll 1
  for (int rep = 0; rep < REPS; ++rep) {

    // =================== Phase 1: softmax denominators =====================
    float lac[8][4];
    #pragma unroll
    for (int h = 0; h < 8; ++h)
      #pragma unroll
      for (int r = 0; r < 4; ++r) lac[h][r] = 0.f;

    #pragma unroll 1
    for (int mt = 0; mt < 16; ++mt) {
      const int m0  = mt << 6;
      const int m0n = (mt < 15) ? m0 + 64 : 0;
      #pragma unroll
      for (int h = 0; h < 8; ++h) {
        uint4 p0, p1, p2; int ht = 0;
        if constexpr (MODE != 3) {
          ht = (h + 3) & 7;
          const bf16* kp = kbase + (size_t)ht * 98304
                         + (size_t)((h < 5) ? m0 : m0n) * 96 + kfragoff;
          p0 = ldg4(kp); p1 = ldg4(kp + 32); p2 = ldg4(kp + 64);
        }
        const int hk = (MODE == 3) ? (h & 3) : h;
        const uint4 q0 = *(const uint4*)&Qsm[h][qrow][quad * 8];
        const uint4 q1 = *(const uint4*)&Qsm[h][qrow][32 + quad * 8];
        const uint4 q2 = *(const uint4*)&Qsm[h][qrow][64 + quad * 8];
        f32x4 acc = {0.f, 0.f, 0.f, 0.f};
        acc = mfma16(q0, kf[hk][0], acc);
        acc = mfma16(q1, kf[hk][1], acc);
        acc = mfma16(q2, kf[hk][2], acc);
        if constexpr (MODE != 3) { kf[ht][0] = p0; kf[ht][1] = p1; kf[ht][2] = p2; }
        #pragma unroll
        for (int r = 0; r < 4; ++r)
          lac[h][r] += __expf(fminf(acc[r] * SCALE, 25.f));
      }
    }
    // reduce over the 16 m-columns (l15) inside each quad-group
    #pragma unroll
    for (int h = 0; h < 8; ++h)
      #pragma unroll
      for (int off = 1; off < 16; off <<= 1)
        #pragma unroll
        for (int r = 0; r < 4; ++r) lac[h][r] += __shfl_xor(lac[h][r], off);
    if (l15 == 0) {
      #pragma unroll
      for (int h = 0; h < 8; ++h)
        #pragma unroll
        for (int r = 0; r < 4; ++r)
          atomicAdd(&Lsm[h][nh * 16 + quad * 4 + r], lac[h][r]);
    }
    __syncthreads();
    if (t < 256) Linv[t >> 5][t & 31] = 1.f / Lsm[t >> 5][t & 31];
    __syncthreads();

    // =================== Phase 2: QK -> mix -> PV ==========================
    // kf[0..2] already hold m-tile 0, heads 0..2 (loaded by phase-1 tail).
    #pragma unroll 1
    for (int mt = 0; mt < 16; ++mt) {
      const int m0  = mt << 6;
      const int m0n = (mt < 15) ? m0 + 64 : m0;

      float aloc[8][4];
      #pragma unroll
      for (int g = 0; g < 8; ++g)
        #pragma unroll
        for (int r = 0; r < 4; ++r) aloc[g][r] = 0.f;

      #pragma unroll
      for (int h = 0; h < 8; ++h) {
        uint4 p0, p1, p2; int ht = 0;
        if constexpr (MODE != 3) {
          ht = (h + 3) & 7;
          const bf16* kp = kbase + (size_t)ht * 98304
                         + (size_t)((h < 5) ? m0 : m0n) * 96 + kfragoff;
          p0 = ldg4(kp); p1 = ldg4(kp + 32); p2 = ldg4(kp + 64);
        }
        const int hk = (MODE == 3) ? (h & 3) : h;
        const uint4 q0 = *(const uint4*)&Qsm[h][qrow][quad * 8];
        const uint4 q1 = *(const uint4*)&Qsm[h][qrow][32 + quad * 8];
        const uint4 q2 = *(const uint4*)&Qsm[h][qrow][64 + quad * 8];
        f32x4 acc = {0.f, 0.f, 0.f, 0.f};
        acc = mfma16(q0, kf[hk][0], acc);
        acc = mfma16(q1, kf[hk][1], acc);
        acc = mfma16(q2, kf[hk][2], acc);
        if constexpr (MODE != 3) { kf[ht][0] = p0; kf[ht][1] = p1; kf[ht][2] = p2; }

        const f32x4 li  = *(const f32x4*)&Linv[h][nrow];
        const f32x4 wlo = *(const f32x4*)&Wm[h][0];
        const f32x4 whi = *(const f32x4*)&Wm[h][4];
        float p[4];
        #pragma unroll
        for (int r = 0; r < 4; ++r)
          p[r] = __expf(fminf(acc[r] * SCALE, 25.f)) * li[r];
        #pragma unroll
        for (int g = 0; g < 4; ++g)
          #pragma unroll
          for (int r = 0; r < 4; ++r) {
            aloc[g][r]     = fmaf(p[r], wlo[g], aloc[g][r]);
            aloc[g + 4][r] = fmaf(p[r], whi[g], aloc[g + 4][r]);
          }
      }

      // V frags for this wave's output head g=w: issue all 12 loads now so the
      // latency hides under the Am write + barrier (register loads cross barriers).
      if constexpr (MODE != 3) {
        #pragma unroll
        for (int dt = 0; dt < 6; ++dt) {
          const bf16* vp = vt + (((size_t)(b * 8 + w)) * 96 + dt * 16 + l15) * 1024
                         + m0 + quad * 8;
          vf[dt][0] = ldg4(vp); vf[dt][1] = ldg4(vp + 32);
        }
      }

      // a_final -> Am (bf16, XOR-swizzled columns)
      #pragma unroll
      for (int g = 0; g < 8; ++g) {
        const float iv = invg[g], cc = cg[g];
        #pragma unroll
        for (int r = 0; r < 4; ++r) {
          const int n = nrow + r;
          const int m = (mq * 16 + l15) ^ ((n & 7) << 3);
          Am[g][n][m] = __float2bfloat16(fmaf(iv, aloc[g][r], cc));
        }
      }
      __syncthreads();

      // PV: wave w handles output head g = w, both n-halves, 6 d-tiles
      #pragma unroll
      for (int nn2 = 0; nn2 < 2; ++nn2) {
        const int arow = nn2 * 16 + l15;
        const int sw   = (arow & 7) << 3;
        const uint4 a0 = *(const uint4*)&Am[w][arow][(quad * 8) ^ sw];
        const uint4 a1 = *(const uint4*)&Am[w][arow][(32 + quad * 8) ^ sw];
        #pragma unroll
        for (int dt = 0; dt < 6; ++dt) {
          oacc[nn2][dt] = mfma16(a0, vf[dt][0], oacc[nn2][dt]);
          oacc[nn2][dt] = mfma16(a1, vf[dt][1], oacc[nn2][dt]);
        }
      }
      __syncthreads();
    }
  }

  // ---- write X once, pre-split hi/lo bf16 for proj3 ----
  const size_t xbase = ((size_t)(b * 1024 + n0)) * 768;
  #pragma unroll
  for (int nn2 = 0; nn2 < 2; ++nn2)
    #pragma unroll
    for (int dt = 0; dt < 6; ++dt)
      #pragma unroll
      for (int r = 0; r < 4; ++r) {
        const size_t idx = xbase + (size_t)(nn2 * 16 + quad * 4 + r) * 768
                         + w * 96 + dt * 16 + l15;
        ushort hs, ls;
        splitw(oacc[nn2][dt][r], hs, ls);
        Xh[idx] = hs; Xl[idx] = ls;
      }
}

// ---------------------------------------------------------------------------
// Kernel S2: transpose + split proj_w: WT[n][k] = W[k][n] as hi/lo bf16.
// ---------------------------------------------------------------------------
__global__ __launch_bounds__(256) void wsplit_kernel(
    const float* __restrict__ pw, ushort* __restrict__ WhT, ushort* __restrict__ WlT)
{
  __shared__ float T[32][33];
  const int t  = threadIdx.x;
  const int kt = (blockIdx.x % 24) * 32;
  const int nt = (blockIdx.x / 24) * 32;
  #pragma unroll
  for (int it = 0; it < 4; ++it) {
    const int i = t + it * 256;
    const int r = i >> 5, c = i & 31;
    T[r][c] = pw[(size_t)(kt + r) * 768 + nt + c];
  }
  __syncthreads();
  #pragma unroll
  for (int it = 0; it < 4; ++it) {
    const int i = t + it * 256;
    const int r = i >> 5, c = i & 31;
    const float x = T[c][r];
    ushort hs, ls;
    splitw(x, hs, ls);
    WhT[(size_t)(nt + r) * 768 + kt + c] = hs;
    WlT[(size_t)(nt + r) * 768 + kt + c] = ls;
  }
}

// ---------------------------------------------------------------------------
// Kernel D: out = X @ proj_w + proj_b via 3-term split-bf16 MFMA.
// 128x128 tiles (was 64x64): X panels re-read 6x (was 12x), W panels 64x
// (was 128x) -> ~300 MB demand (was ~600 MB). 512 thr / 8 waves, wave =
// 64x32 output. LDS 72 KB -> 2 blocks/CU. Same [r][36] bank-safe layout.
// ---------------------------------------------------------------------------
__global__ __launch_bounds__(512) void proj3_kernel(
    const ushort* __restrict__ Xh, const ushort* __restrict__ Xl,
    const ushort* __restrict__ WhT, const ushort* __restrict__ WlT,
    const float* __restrict__ pb, float* __restrict__ out)
{
  __shared__ unsigned Ah[128][36], Al[128][36], Bh[128][36], Bl[128][36];
  const int t    = threadIdx.x;
  const int bc   = blockIdx.x % 6, br = blockIdx.x / 6;
  const int row0 = br * 128, col0 = bc * 128;
  const int w    = t >> 6;            // wave 0..7
  const int lane = t & 63;
  const int l15  = lane & 15;
  const int quad = lane >> 4;
  const int wr   = w >> 2;            // 0..1  (64-row half)
  const int wc   = w & 3;             // 0..3  (32-col quarter)

  f32x4 acc[4][2];
  #pragma unroll
  for (int i = 0; i < 4; ++i)
    #pragma unroll
    for (int j = 0; j < 2; ++j) acc[i][j] = (f32x4){0.f, 0.f, 0.f, 0.f};

  for (int kt = 0; kt < 768; kt += 64) {
    __syncthreads();
    #pragma unroll
    for (int it = 0; it < 2; ++it) {
      const int i = t + it * 512;          // 0..1023
      const int r = i >> 3, j = i & 7;     // r: 0..127, j: 0..7 (8 uint4/row)
      ((uint4*)&Ah[r][0])[j] = *(const uint4*)(Xh + (size_t)(row0 + r) * 768 + kt + j * 8);
      ((uint4*)&Al[r][0])[j] = *(const uint4*)(Xl + (size_t)(row0 + r) * 768 + kt + j * 8);
      ((uint4*)&Bh[r][0])[j] = *(const uint4*)(WhT + (size_t)(col0 + r) * 768 + kt + j * 8);
      ((uint4*)&Bl[r][0])[j] = *(const uint4*)(WlT + (size_t)(col0 + r) * 768 + kt + j * 8);
    }
    __syncthreads();
    #pragma unroll
    for (int ks = 0; ks < 2; ++ks) {
      const int ko = ks * 16 + quad * 4;
      uint4 ah[4], al[4], bh[2], bl[2];
      #pragma unroll
      for (int i = 0; i < 4; ++i) {
        ah[i] = *(const uint4*)&Ah[wr * 64 + i * 16 + l15][ko];
        al[i] = *(const uint4*)&Al[wr * 64 + i * 16 + l15][ko];
      }
      #pragma unroll
      for (int j = 0; j < 2; ++j) {
        bh[j] = *(const uint4*)&Bh[wc * 32 + j * 16 + l15][ko];
        bl[j] = *(const uint4*)&Bl[wc * 32 + j * 16 + l15][ko];
      }
      #pragma unroll
      for (int i = 0; i < 4; ++i)
        #pragma unroll
        for (int j = 0; j < 2; ++j) {
          acc[i][j] = mfma16(ah[i], bh[j], acc[i][j]);
          acc[i][j] = mfma16(al[i], bh[j], acc[i][j]);
          acc[i][j] = mfma16(ah[i], bl[j], acc[i][j]);
        }
    }
  }

  #pragma unroll
  for (int i = 0; i < 4; ++i)
    #pragma unroll
    for (int j = 0; j < 2; ++j) {
      const int col = col0 + wc * 32 + j * 16 + l15;
      const float bias = pb[col];
      #pragma unroll
      for (int r = 0; r < 4; ++r)
        out[(size_t)(row0 + wr * 64 + i * 16 + quad * 4 + r) * 768 + col] = acc[i][j][r] + bias;
    }
}

// ---------------------------------------------------------------------------
extern "C" void kernel_launch(void* const* d_in, const int* in_sizes, int n_in,
                              void* d_out, int out_size, void* d_ws, size_t ws_size,
                              hipStream_t stream)
{
  const float* q  = (const float*)d_in[0];
  const float* k  = (const float*)d_in[1];
  const float* v  = (const float*)d_in[2];
  const float* cw = (const float*)d_in[3];
  const float* rw = (const float*)d_in[4];
  const float* rb = (const float*)d_in[5];
  const float* bg = (const float*)d_in[6];
  const float* bb = (const float*)d_in[7];
  const float* bm = (const float*)d_in[8];
  const float* bv = (const float*)d_in[9];
  const float* pw = (const float*)d_in[10];
  const float* pb = (const float*)d_in[11];
  float* out = (float*)d_out;

  char* ws = (char*)d_ws;
  bf16*   qh = (bf16*)(ws);                        // 12,582,912 B
  bf16*   kh = (bf16*)(ws + 12582912);             // 12,582,912 B
  bf16*   vt = (bf16*)(ws + 25165824);             // 12,582,912 B (V^T)
  ushort* Xh = (ushort*)(ws + 37748736);           // 12,582,912 B (attn out, hi bf16)
  ushort* Xl = (ushort*)(ws + 50331648);           // 12,582,912 B (attn out, lo bf16)
  bf16*   vhT = (bf16*)(ws + 37748736);            // temp vh, dead after vtrans
  // live only after attn (vt dead):
  ushort* WhT = (ushort*)vt;                       // 1,179,648 B
  ushort* WlT = (ushort*)((char*)vt + 1179648);    // 1,179,648 B

  conv_kernel<<<8192, 256, 0, stream>>>(q, k, v, cw, qh, kh, vhT);
  vtrans_kernel<<<1024, 256, 0, stream>>>(vhT, vt);
  attn_fused_t<0><<<256, 512, 0, stream>>>(qh, kh, vt, rw, rb, bg, bb, bm, bv, Xh, Xl);
  wsplit_kernel<<<576, 256, 0, stream>>>(pw, WhT, WlT);
  proj3_kernel<<<384, 512, 0, stream>>>(Xh, Xl, WhT, WlT, pb, out);
}

// Round 19
// 343.311 us; speedup vs baseline: 1.0441x; 1.0441x over previous
//
#include <hip/hip_runtime.h>
#include <hip/hip_bf16.h>
#include <stdint.h>

typedef __hip_bfloat16 bf16;
typedef __attribute__((ext_vector_type(8))) short short8;  // 8 bf16 = 4 VGPR
typedef __attribute__((ext_vector_type(4))) float f32x4;

#define DEVFN __device__ __forceinline__

// B=8, N=1024, DIM=768, HEADS=8, HEAD_DIM=96, S=16, CH=3. fp32 in/out.
constexpr float SCALE = 0.10206207261596577f;   // 96^-0.5

DEVFN short8 as_s8(uint4 u) { union { uint4 a; short8 b; } x; x.a = u; return x.b; }

DEVFN f32x4 mfma16(uint4 a, uint4 b, f32x4 c) {
  return __builtin_amdgcn_mfma_f32_16x16x32_bf16(as_s8(a), as_s8(b), c, 0, 0, 0);
}

DEVFN uint4 ldg4(const bf16* p) { return *(const uint4*)p; }

DEVFN void splitw(float x, ushort& h, ushort& l) {
  const float hi = __bfloat162float(__float2bfloat16(x));
  h = (ushort)(__float_as_uint(hi) >> 16);
  l = (ushort)(__float_as_uint(__bfloat162float(__float2bfloat16(x - hi))) >> 16);
}

// ---------------------------------------------------------------------------
// Kernel A: 3x3 SAME conv on (16,16,3) image view; head = y>>1,
// d = (y&1)*48 + x*3 + c.  fp32 in -> bf16 qh/kh/vh [B*H][1024][96].
// ---------------------------------------------------------------------------
__global__ __launch_bounds__(256) void conv_kernel(
    const float* __restrict__ q, const float* __restrict__ k, const float* __restrict__ v,
    const float* __restrict__ cw,
    bf16* __restrict__ qh, bf16* __restrict__ kh, bf16* __restrict__ vh)
{
  __shared__ float img[3][768];
  __shared__ float wsm[81];
  const int t = threadIdx.x;
  const size_t pos = blockIdx.x;
  const int b = blockIdx.x >> 10;
  const int n = blockIdx.x & 1023;

  {
    const float* s0 = q + pos * 768;
    const float* s1 = k + pos * 768;
    const float* s2 = v + pos * 768;
    img[0][t] = s0[t]; img[0][t + 256] = s0[t + 256]; img[0][t + 512] = s0[t + 512];
    img[1][t] = s1[t]; img[1][t + 256] = s1[t + 256]; img[1][t + 512] = s1[t + 512];
    img[2][t] = s2[t]; img[2][t + 256] = s2[t + 256]; img[2][t + 512] = s2[t + 512];
  }
  if (t < 81) wsm[t] = cw[t];
  __syncthreads();

  const int x    = t & 15;
  const int y    = t >> 4;
  const int head = y >> 1;
  const int d0   = (y & 1) * 48 + x * 3;
  const size_t obase = (((size_t)(b * 8 + head)) * 1024 + n) * 96 + d0;

  #pragma unroll
  for (int s3 = 0; s3 < 3; ++s3) {
    float a0 = 0.f, a1 = 0.f, a2 = 0.f;
    #pragma unroll
    for (int dy = 0; dy < 3; ++dy) {
      const int iy = y + dy - 1;
      if ((unsigned)iy < 16u) {
        #pragma unroll
        for (int dx = 0; dx < 3; ++dx) {
          const int ix = x + dx - 1;
          if ((unsigned)ix < 16u) {
            const int ib = iy * 48 + ix * 3;
            const int wb = (dy * 3 + dx) * 9;
            #pragma unroll
            for (int ci = 0; ci < 3; ++ci) {
              const float val = img[s3][ib + ci];
              a0 = fmaf(val, wsm[wb + ci * 3 + 0], a0);
              a1 = fmaf(val, wsm[wb + ci * 3 + 1], a1);
              a2 = fmaf(val, wsm[wb + ci * 3 + 2], a2);
            }
          }
        }
      }
    }
    bf16* dst = (s3 == 0) ? qh : (s3 == 1) ? kh : vh;
    dst[obase]     = __float2bfloat16(a0);
    dst[obase + 1] = __float2bfloat16(a1);
    dst[obase + 2] = __float2bfloat16(a2);
  }
}

// ---------------------------------------------------------------------------
// Kernel T: transpose vh [bg][1024 n][96 d] -> vt [bg][96 d][1024 n] (bf16)
// ---------------------------------------------------------------------------
__global__ __launch_bounds__(256) void vtrans_kernel(
    const bf16* __restrict__ vh, bf16* __restrict__ vt)
{
  __shared__ unsigned T[64][52];
  const int t = threadIdx.x;
  const int bg = blockIdx.x >> 4;
  const int n0 = (blockIdx.x & 15) << 6;
  const bf16* src = vh + ((size_t)bg * 1024 + n0) * 96;
  #pragma unroll
  for (int it = 0; it < 3; ++it) {
    const int i = t + it * 256;
    const int r = i / 12, j = i - r * 12;
    ((uint4*)&T[r][0])[j] = ((const uint4*)(src + (size_t)r * 96))[j];
  }
  __syncthreads();
  #pragma unroll
  for (int it = 0; it < 3; ++it) {
    const int i = t + it * 256;
    const int d = i >> 3, c = i & 7;
    unsigned wo[4];
    #pragma unroll
    for (int p = 0; p < 4; ++p) {
      const unsigned lo = T[c * 8 + p * 2    ][d >> 1];
      const unsigned hi = T[c * 8 + p * 2 + 1][d >> 1];
      const unsigned a  = (d & 1) ? (lo >> 16)          : (lo & 0xffffu);
      const unsigned bs = (d & 1) ? (hi & 0xffff0000u)  : (hi << 16);
      wo[p] = a | bs;
    }
    uint4 out4; out4.x = wo[0]; out4.y = wo[1]; out4.z = wo[2]; out4.w = wo[3];
    *(uint4*)(vt + ((size_t)bg * 96 + d) * 1024 + n0 + c * 8) = out4;
  }
}

// ---------------------------------------------------------------------------
// Kernel F: fused attention — EXACT R2 structure (155.5 µs proven):
// one block per (b, 32-row n-tile); 8 waves; wave w = (nh=w>>2, mq=w&3);
// K frags depth-3 pipelined; single Am + two barriers per m-tile; V batch-
// issued 12-deep before the Am barrier. Epilogue writes X pre-split as
// hi/lo bf16 (Xh/Xl) for proj3 (identical numerics to fp32->split2 path).
//
// MODE 0 = real kernel. MODE 3 (stale-K/V compute-floor probe) retained in
// source for a future ablation round; NOT instantiated this round.
// ---------------------------------------------------------------------------
template<int MODE>
__global__ __launch_bounds__(512, 2) void attn_fused_t(
    const bf16* __restrict__ qh, const bf16* __restrict__ kh, const bf16* __restrict__ vt,
    const float* __restrict__ rw, const float* __restrict__ rb,
    const float* __restrict__ bng, const float* __restrict__ bnb,
    const float* __restrict__ bnm, const float* __restrict__ bnv,
    ushort* __restrict__ Xh, ushort* __restrict__ Xl)
{
  constexpr int REPS = (MODE == 3) ? 2 : 1;

  __shared__ bf16  Qsm[8][32][104];   // 53,248 B (pad 104: 8 distinct bank starts)
  __shared__ bf16  Am[8][32][64];     // 32,768 B (m XOR-swizzled by (n&7)<<3)
  __shared__ float Lsm[8][32];
  __shared__ float Linv[8][32];
  __shared__ float Wm[8][8];
  __shared__ float invg[8], cg[8];

  const int t    = threadIdx.x;
  const int b    = blockIdx.x & 7;    // XCD swizzle: batch b -> XCD b
  const int nt   = blockIdx.x >> 3;   // 0..31
  const int n0   = nt << 5;
  const int w    = t >> 6;            // wave 0..7
  const int lane = t & 63;
  const int l15  = lane & 15;
  const int quad = lane >> 4;
  const int nh   = w >> 2;            // QK n-half (0,1)
  const int mq   = w & 3;             // QK m-quadrant (0..3)

  // ---- stage Q (8 heads x 32 rows x 96) into LDS ----
  {
    const int row  = t >> 1;          // 0..255 = h*32 + n
    const int half = t & 1;
    const int hh = row >> 5, nn = row & 31;
    const bf16* src = qh + (((size_t)(b * 8 + hh)) * 1024 + n0 + nn) * 96 + half * 48;
    bf16* dst = &Qsm[hh][nn][half * 48];
    #pragma unroll
    for (int j = 0; j < 6; ++j)
      ((uint4*)dst)[j] = ((const uint4*)src)[j];
  }
  if (t < 64) Wm[t >> 3][t & 7] = rw[t];
  if (t < 8) {
    const float iv = bng[t] * rsqrtf(bnv[t] + 1e-3f);
    invg[t] = iv;
    cg[t]   = iv * (rb[t] - bnm[t]) + bnb[t];
  }
  if (t < 256) Lsm[t >> 5][t & 31] = 0.f;
  __syncthreads();

  const bf16* kbase = kh + (size_t)(b * 8) * 98304;           // 1024*96 per head
  const size_t kfragoff = (size_t)(mq * 16 + l15) * 96 + quad * 8;
  const int qrow = nh * 16 + l15;

  // ---- K frag pipeline: kf[h] = 3 x uint4 covering k=0..95 for head h ----
  uint4 kf[8][3];
  #pragma unroll
  for (int hp = 0; hp < ((MODE == 3) ? 4 : 3); ++hp) {
    const bf16* kp = kbase + (size_t)hp * 98304 + kfragoff;   // mt=0
    kf[hp][0] = ldg4(kp); kf[hp][1] = ldg4(kp + 32); kf[hp][2] = ldg4(kp + 64);
  }

  uint4 vf[6][2];
  if constexpr (MODE == 3) {       // stale V: loaded once, reused every m-tile
    #pragma unroll
    for (int dt = 0; dt < 6; ++dt) {
      const bf16* vp = vt + (((size_t)(b * 8 + w)) * 96 + dt * 16 + l15) * 1024 + quad * 8;
      vf[dt][0] = ldg4(vp); vf[dt][1] = ldg4(vp + 32);
    }
  }

  f32x4 oacc[2][6];
  #pragma unroll
  for (int i = 0; i < 2; ++i)
    #pragma unroll
    for (int j = 0; j < 6; ++j) oacc[i][j] = (f32x4){0.f, 0.f, 0.f, 0.f};

  const int nrow = nh * 16 + quad * 4;

  #pragma unroll 1
  for (int rep = 0; rep < REPS; ++rep) {

    // =================== Phase 1: softmax denominators =====================
    float lac[8][4];
    #pragma unroll
    for (int h = 0; h < 8; ++h)
      #pragma unroll
      for (int r = 0; r < 4; ++r) lac[h][r] = 0.f;

    #pragma unroll 1
    for (int mt = 0; mt < 16; ++mt) {
      const int m0  = mt << 6;
      const int m0n = (mt < 15) ? m0 + 64 : 0;
      #pragma unroll
      for (int h = 0; h < 8; ++h) {
        uint4 p0, p1, p2; int ht = 0;
        if constexpr (MODE != 3) {
          ht = (h + 3) & 7;
          const bf16* kp = kbase + (size_t)ht * 98304
                         + (size_t)((h < 5) ? m0 : m0n) * 96 + kfragoff;
          p0 = ldg4(kp); p1 = ldg4(kp + 32); p2 = ldg4(kp + 64);
        }
        const int hk = (MODE == 3) ? (h & 3) : h;
        const uint4 q0 = *(const uint4*)&Qsm[h][qrow][quad * 8];
        const uint4 q1 = *(const uint4*)&Qsm[h][qrow][32 + quad * 8];
        const uint4 q2 = *(const uint4*)&Qsm[h][qrow][64 + quad * 8];
        f32x4 acc = {0.f, 0.f, 0.f, 0.f};
        acc = mfma16(q0, kf[hk][0], acc);
        acc = mfma16(q1, kf[hk][1], acc);
        acc = mfma16(q2, kf[hk][2], acc);
        if constexpr (MODE != 3) { kf[ht][0] = p0; kf[ht][1] = p1; kf[ht][2] = p2; }
        #pragma unroll
        for (int r = 0; r < 4; ++r)
          lac[h][r] += __expf(fminf(acc[r] * SCALE, 25.f));
      }
    }
    // reduce over the 16 m-columns (l15) inside each quad-group
    #pragma unroll
    for (int h = 0; h < 8; ++h)
      #pragma unroll
      for (int off = 1; off < 16; off <<= 1)
        #pragma unroll
        for (int r = 0; r < 4; ++r) lac[h][r] += __shfl_xor(lac[h][r], off);
    if (l15 == 0) {
      #pragma unroll
      for (int h = 0; h < 8; ++h)
        #pragma unroll
        for (int r = 0; r < 4; ++r)
          atomicAdd(&Lsm[h][nh * 16 + quad * 4 + r], lac[h][r]);
    }
    __syncthreads();
    if (t < 256) Linv[t >> 5][t & 31] = 1.f / Lsm[t >> 5][t & 31];
    __syncthreads();

    // =================== Phase 2: QK -> mix -> PV ==========================
    // kf[0..2] already hold m-tile 0, heads 0..2 (loaded by phase-1 tail).
    #pragma unroll 1
    for (int mt = 0; mt < 16; ++mt) {
      const int m0  = mt << 6;
      const int m0n = (mt < 15) ? m0 + 64 : m0;

      float aloc[8][4];
      #pragma unroll
      for (int g = 0; g < 8; ++g)
        #pragma unroll
        for (int r = 0; r < 4; ++r) aloc[g][r] = 0.f;

      #pragma unroll
      for (int h = 0; h < 8; ++h) {
        uint4 p0, p1, p2; int ht = 0;
        if constexpr (MODE != 3) {
          ht = (h + 3) & 7;
          const bf16* kp = kbase + (size_t)ht * 98304
                         + (size_t)((h < 5) ? m0 : m0n) * 96 + kfragoff;
          p0 = ldg4(kp); p1 = ldg4(kp + 32); p2 = ldg4(kp + 64);
        }
        const int hk = (MODE == 3) ? (h & 3) : h;
        const uint4 q0 = *(const uint4*)&Qsm[h][qrow][quad * 8];
        const uint4 q1 = *(const uint4*)&Qsm[h][qrow][32 + quad * 8];
        const uint4 q2 = *(const uint4*)&Qsm[h][qrow][64 + quad * 8];
        f32x4 acc = {0.f, 0.f, 0.f, 0.f};
        acc = mfma16(q0, kf[hk][0], acc);
        acc = mfma16(q1, kf[hk][1], acc);
        acc = mfma16(q2, kf[hk][2], acc);
        if constexpr (MODE != 3) { kf[ht][0] = p0; kf[ht][1] = p1; kf[ht][2] = p2; }

        const f32x4 li  = *(const f32x4*)&Linv[h][nrow];
        const f32x4 wlo = *(const f32x4*)&Wm[h][0];
        const f32x4 whi = *(const f32x4*)&Wm[h][4];
        float p[4];
        #pragma unroll
        for (int r = 0; r < 4; ++r)
          p[r] = __expf(fminf(acc[r] * SCALE, 25.f)) * li[r];
        #pragma unroll
        for (int g = 0; g < 4; ++g)
          #pragma unroll
          for (int r = 0; r < 4; ++r) {
            aloc[g][r]     = fmaf(p[r], wlo[g], aloc[g][r]);
            aloc[g + 4][r] = fmaf(p[r], whi[g], aloc[g + 4][r]);
          }
      }

      // V frags for this wave's output head g=w: issue all 12 loads now so the
      // latency hides under the Am write + barrier (register loads cross barriers).
      if constexpr (MODE != 3) {
        #pragma unroll
        for (int dt = 0; dt < 6; ++dt) {
          const bf16* vp = vt + (((size_t)(b * 8 + w)) * 96 + dt * 16 + l15) * 1024
                         + m0 + quad * 8;
          vf[dt][0] = ldg4(vp); vf[dt][1] = ldg4(vp + 32);
        }
      }

      // a_final -> Am (bf16, XOR-swizzled columns)
      #pragma unroll
      for (int g = 0; g < 8; ++g) {
        const float iv = invg[g], cc = cg[g];
        #pragma unroll
        for (int r = 0; r < 4; ++r) {
          const int n = nrow + r;
          const int m = (mq * 16 + l15) ^ ((n & 7) << 3);
          Am[g][n][m] = __float2bfloat16(fmaf(iv, aloc[g][r], cc));
        }
      }
      __syncthreads();

      // PV: wave w handles output head g = w, both n-halves, 6 d-tiles
      #pragma unroll
      for (int nn2 = 0; nn2 < 2; ++nn2) {
        const int arow = nn2 * 16 + l15;
        const int sw   = (arow & 7) << 3;
        const uint4 a0 = *(const uint4*)&Am[w][arow][(quad * 8) ^ sw];
        const uint4 a1 = *(const uint4*)&Am[w][arow][(32 + quad * 8) ^ sw];
        #pragma unroll
        for (int dt = 0; dt < 6; ++dt) {
          oacc[nn2][dt] = mfma16(a0, vf[dt][0], oacc[nn2][dt]);
          oacc[nn2][dt] = mfma16(a1, vf[dt][1], oacc[nn2][dt]);
        }
      }
      __syncthreads();
    }
  }

  // ---- write X once, pre-split hi/lo bf16 for proj3 ----
  const size_t xbase = ((size_t)(b * 1024 + n0)) * 768;
  #pragma unroll
  for (int nn2 = 0; nn2 < 2; ++nn2)
    #pragma unroll
    for (int dt = 0; dt < 6; ++dt)
      #pragma unroll
      for (int r = 0; r < 4; ++r) {
        const size_t idx = xbase + (size_t)(nn2 * 16 + quad * 4 + r) * 768
                         + w * 96 + dt * 16 + l15;
        ushort hs, ls;
        splitw(oacc[nn2][dt][r], hs, ls);
        Xh[idx] = hs; Xl[idx] = ls;
      }
}

// ---------------------------------------------------------------------------
// Kernel S2: transpose + split proj_w: WT[n][k] = W[k][n] as hi/lo bf16.
// ---------------------------------------------------------------------------
__global__ __launch_bounds__(256) void wsplit_kernel(
    const float* __restrict__ pw, ushort* __restrict__ WhT, ushort* __restrict__ WlT)
{
  __shared__ float T[32][33];
  const int t  = threadIdx.x;
  const int kt = (blockIdx.x % 24) * 32;
  const int nt = (blockIdx.x / 24) * 32;
  #pragma unroll
  for (int it = 0; it < 4; ++it) {
    const int i = t + it * 256;
    const int r = i >> 5, c = i & 31;
    T[r][c] = pw[(size_t)(kt + r) * 768 + nt + c];
  }
  __syncthreads();
  #pragma unroll
  for (int it = 0; it < 4; ++it) {
    const int i = t + it * 256;
    const int r = i >> 5, c = i & 31;
    const float x = T[c][r];
    ushort hs, ls;
    splitw(x, hs, ls);
    WhT[(size_t)(nt + r) * 768 + kt + c] = hs;
    WlT[(size_t)(nt + r) * 768 + kt + c] = ls;
  }
}

// ---------------------------------------------------------------------------
// Kernel D: out = X @ proj_w + proj_b via 3-term split-bf16 MFMA.
// 64x64 tiles (measured-best in the 347.1 µs pipeline; 128x128 retile
// regressed to 358.5 µs — load imbalance at 1.5 blocks/CU, traffic not
// the binding constraint). X arrives pre-split -> staging is pure copies.
// ---------------------------------------------------------------------------
__global__ __launch_bounds__(256) void proj3_kernel(
    const ushort* __restrict__ Xh, const ushort* __restrict__ Xl,
    const ushort* __restrict__ WhT, const ushort* __restrict__ WlT,
    const float* __restrict__ pb, float* __restrict__ out)
{
  __shared__ unsigned Ah[64][36], Al[64][36], Bh[64][36], Bl[64][36];
  const int t    = threadIdx.x;
  const int bc   = blockIdx.x % 12, br = blockIdx.x / 12;
  const int row0 = br * 64, col0 = bc * 64;
  const int w    = t >> 6;
  const int lane = t & 63;
  const int l15  = lane & 15;
  const int quad = lane >> 4;
  const int wr   = w >> 1, wc = w & 1;

  f32x4 acc[2][2];
  #pragma unroll
  for (int i = 0; i < 2; ++i)
    #pragma unroll
    for (int j = 0; j < 2; ++j) acc[i][j] = (f32x4){0.f, 0.f, 0.f, 0.f};

  for (int kt = 0; kt < 768; kt += 64) {
    __syncthreads();
    #pragma unroll
    for (int it = 0; it < 2; ++it) {
      const int i = t + it * 256;          // 0..511
      const int r = i >> 3, j = i & 7;
      ((uint4*)&Ah[r][0])[j] = *(const uint4*)(Xh + (size_t)(row0 + r) * 768 + kt + j * 8);
      ((uint4*)&Al[r][0])[j] = *(const uint4*)(Xl + (size_t)(row0 + r) * 768 + kt + j * 8);
      ((uint4*)&Bh[r][0])[j] = *(const uint4*)(WhT + (size_t)(col0 + r) * 768 + kt + j * 8);
      ((uint4*)&Bl[r][0])[j] = *(const uint4*)(WlT + (size_t)(col0 + r) * 768 + kt + j * 8);
    }
    __syncthreads();
    #pragma unroll
    for (int ks = 0; ks < 2; ++ks) {
      const int ko = ks * 16 + quad * 4;
      uint4 ah[2], al[2], bh[2], bl[2];
      #pragma unroll
      for (int i = 0; i < 2; ++i) {
        ah[i] = *(const uint4*)&Ah[wr * 32 + i * 16 + l15][ko];
        al[i] = *(const uint4*)&Al[wr * 32 + i * 16 + l15][ko];
      }
      #pragma unroll
      for (int j = 0; j < 2; ++j) {
        bh[j] = *(const uint4*)&Bh[wc * 32 + j * 16 + l15][ko];
        bl[j] = *(const uint4*)&Bl[wc * 32 + j * 16 + l15][ko];
      }
      #pragma unroll
      for (int i = 0; i < 2; ++i)
        #pragma unroll
        for (int j = 0; j < 2; ++j) {
          acc[i][j] = mfma16(ah[i], bh[j], acc[i][j]);
          acc[i][j] = mfma16(al[i], bh[j], acc[i][j]);
          acc[i][j] = mfma16(ah[i], bl[j], acc[i][j]);
        }
    }
  }

  #pragma unroll
  for (int i = 0; i < 2; ++i)
    #pragma unroll
    for (int j = 0; j < 2; ++j) {
      const int col = col0 + wc * 32 + j * 16 + l15;
      const float bias = pb[col];
      #pragma unroll
      for (int r = 0; r < 4; ++r)
        out[(size_t)(row0 + wr * 32 + i * 16 + quad * 4 + r) * 768 + col] = acc[i][j][r] + bias;
    }
}

// ---------------------------------------------------------------------------
extern "C" void kernel_launch(void* const* d_in, const int* in_sizes, int n_in,
                              void* d_out, int out_size, void* d_ws, size_t ws_size,
                              hipStream_t stream)
{
  const float* q  = (const float*)d_in[0];
  const float* k  = (const float*)d_in[1];
  const float* v  = (const float*)d_in[2];
  const float* cw = (const float*)d_in[3];
  const float* rw = (const float*)d_in[4];
  const float* rb = (const float*)d_in[5];
  const float* bg = (const float*)d_in[6];
  const float* bb = (const float*)d_in[7];
  const float* bm = (const float*)d_in[8];
  const float* bv = (const float*)d_in[9];
  const float* pw = (const float*)d_in[10];
  const float* pb = (const float*)d_in[11];
  float* out = (float*)d_out;

  char* ws = (char*)d_ws;
  bf16*   qh = (bf16*)(ws);                        // 12,582,912 B
  bf16*   kh = (bf16*)(ws + 12582912);             // 12,582,912 B
  bf16*   vt = (bf16*)(ws + 25165824);             // 12,582,912 B (V^T)
  ushort* Xh = (ushort*)(ws + 37748736);           // 12,582,912 B (attn out, hi bf16)
  ushort* Xl = (ushort*)(ws + 50331648);           // 12,582,912 B (attn out, lo bf16)
  bf16*   vhT = (bf16*)(ws + 37748736);            // temp vh, dead after vtrans
  // live only after attn (vt dead):
  ushort* WhT = (ushort*)vt;                       // 1,179,648 B
  ushort* WlT = (ushort*)((char*)vt + 1179648);    // 1,179,648 B

  conv_kernel<<<8192, 256, 0, stream>>>(q, k, v, cw, qh, kh, vhT);
  vtrans_kernel<<<1024, 256, 0, stream>>>(vhT, vt);
  attn_fused_t<0><<<256, 512, 0, stream>>>(qh, kh, vt, rw, rb, bg, bb, bm, bv, Xh, Xl);
  wsplit_kernel<<<576, 256, 0, stream>>>(pw, WhT, WlT);
  proj3_kernel<<<1536, 256, 0, stream>>>(Xh, Xl, WhT, WlT, pb, out);
}